// Round 2
// baseline (366.320 us; speedup 1.0000x reference)
//
#include <hip/hip_runtime.h>
#include <hip/hip_bf16.h>

// m=64 sample rows + 1 target row = 65 rows of N = 524288 f32.
// Everything reduces to the 65x65 Gram matrix; epilogue is O(m^2) scalar math.
// time_points (d_in[2]) cancels in all pairwise differences -> unused.
//
// R2 design: NO LDS staging in the hot loop (each element is used exactly
// once -> staging was pure latency, R1 was 8.6% HBM / 21% occupancy /
// barrier-bound). Lanes load MFMA fragments straight from global (f32x4 x2 =
// 32B/lane; lane groups {l,l+16,l+32,l+48} cover 128B contiguous per row),
// cvt to bf16 in regs, 15 upper-triangle 16x16x32 MFMAs. No barriers until
// the final block reduction.
#define NROW 65
#define GP   80            // padded gram dim (5 tiles of 16)
#define GE   (GP * GP)     // 6400 f32 per gram copy
#define TPB  512           // 8 waves per block
#define GRID 384           // 3072 waves total = 12 waves/CU, all co-resident
#define EPT  256           // epilogue threads

typedef float  f32x4  __attribute__((ext_vector_type(4)));
typedef __bf16 bf16x8 __attribute__((ext_vector_type(8)));

__global__ void zero_ws(float* __restrict__ p, int n) {
  int i = blockIdx.x * blockDim.x + threadIdx.x;
  int stride = gridDim.x * blockDim.x;
  for (; i < n; i += stride) p[i] = 0.f;
}

__global__ __launch_bounds__(TPB, 3) void gram_k(
    const float* __restrict__ X,   // [64][Nk] f32
    const float* __restrict__ T,   // [Nk] f32
    float* __restrict__ G,         // ncopies * GE f32 accumulators (zeroed)
    int ncopies, int Nk, int total_steps)
{
  __shared__ float gl[GE];         // 25.6 KB, used only for the final reduce
  const int tid  = threadIdx.x;
  const int wv   = tid >> 6;
  const int lane = tid & 63;
  const int lr   = lane & 15;          // fragment row within tile
  const int lko  = (lane >> 4) * 8;    // fragment k-offset (8 elems)

  f32x4 acc[15];                   // upper-triangle 16x16 tiles (I<=J)
#pragma unroll
  for (int i = 0; i < 15; ++i) acc[i] = (f32x4){0.f, 0.f, 0.f, 0.f};

  const int nwaves = GRID * (TPB / 64);
  const int gwave  = blockIdx.x * (TPB / 64) + wv;

  for (int s = gwave; s < total_steps; s += nwaves) {
    const int k = s * 32 + lko;
    bf16x8 f[5];
    // Tiles 0..3: rows 0..63 of X, unconditional.
#pragma unroll
    for (int t = 0; t < 4; ++t) {
      const float* p = X + (size_t)(t * 16 + lr) * Nk + k;
      f32x4 a = *(const f32x4*)p;
      f32x4 b = *(const f32x4*)(p + 4);
      f[t] = (bf16x8){(__bf16)a.x, (__bf16)a.y, (__bf16)a.z, (__bf16)a.w,
                      (__bf16)b.x, (__bf16)b.y, (__bf16)b.z, (__bf16)b.w};
    }
    // Tile 4: row 64 = target (only lr==0 lanes load; lanes 0/16/32/48 cover
    // 128B contiguous of T), rows 65..79 = zero pad.
    {
      bf16x8 z = (bf16x8){(__bf16)0.f, (__bf16)0.f, (__bf16)0.f, (__bf16)0.f,
                          (__bf16)0.f, (__bf16)0.f, (__bf16)0.f, (__bf16)0.f};
      if (lr == 0) {
        const float* p = T + k;
        f32x4 a = *(const f32x4*)p;
        f32x4 b = *(const f32x4*)(p + 4);
        z = (bf16x8){(__bf16)a.x, (__bf16)a.y, (__bf16)a.z, (__bf16)a.w,
                     (__bf16)b.x, (__bf16)b.y, (__bf16)b.z, (__bf16)b.w};
      }
      f[4] = z;
    }
#pragma unroll
    for (int I = 0; I < 5; ++I)
#pragma unroll
      for (int J = I; J < 5; ++J) {
        const int idx = I * 5 + J - (I * (I + 1)) / 2;   // compile-time
        acc[idx] = __builtin_amdgcn_mfma_f32_16x16x32_bf16(f[I], f[J], acc[idx], 0, 0, 0);
      }
  }

  // Block reduction: 8 waves atomic-add partials into LDS [80][80], then
  // ~2145 global atomics per block (i<=j, j<65) into 1 of ncopies buffers.
  for (int e = tid; e < GE; e += TPB) gl[e] = 0.f;
  __syncthreads();
#pragma unroll
  for (int I = 0; I < 5; ++I)
#pragma unroll
    for (int J = I; J < 5; ++J) {
      const int idx = I * 5 + J - (I * (I + 1)) / 2;
#pragma unroll
      for (int r = 0; r < 4; ++r) {
        int grow = I * 16 + (lane >> 4) * 4 + r;  // C/D: row=(lane>>4)*4+reg
        int gcol = J * 16 + lr;                   //      col=lane&15
        atomicAdd(&gl[grow * GP + gcol], acc[idx][r]);
      }
    }
  __syncthreads();
  float* dst = G + (size_t)(blockIdx.x % ncopies) * GE;
  for (int e = tid; e < GE; e += TPB) {
    int i = e / GP, j = e % GP;
    if (j < NROW && i <= j) atomicAdd(dst + e, gl[e]);
  }
}

__global__ __launch_bounds__(EPT) void epilogue_k(
    const float* __restrict__ G, int ncopies, float* __restrict__ out)
{
  __shared__ float gl[GE];
  __shared__ float rx[4], rt[4];
  const int tid = threadIdx.x;
  for (int e = tid; e < GE; e += EPT) {
    float s = 0.f;
    for (int c = 0; c < ncopies; ++c) s += G[(size_t)c * GE + e];
    gl[e] = s;
  }
  __syncthreads();

  float accX = 0.f, accT = 0.f;
  for (int e = tid; e < GE; e += EPT) {
    int i = e / GP, j = e % GP;
    if (j >= NROW || i >= j) continue;           // upper triangle, i<j
    float g  = gl[e];
    float d2 = gl[i * GP + i] + gl[j * GP + j] - 2.f * g;
    if (j < 64) {                                // pair term (i<j<64)
      accX += expf(-fmaxf(d2, 0.f));             // ref clamps d2 at 0
    } else {                                     // j==64: target term
      accT += expf(-d2);                         // ref does not clamp dt2
    }
  }
#pragma unroll
  for (int off = 32; off > 0; off >>= 1) {
    accX += __shfl_down(accX, off);
    accT += __shfl_down(accT, off);
  }
  const int wv = tid >> 6, lane = tid & 63;
  if (lane == 0) { rx[wv] = accX; rt[wv] = accT; }
  __syncthreads();
  if (tid == 0) {
    float sx = rx[0] + rx[1] + rx[2] + rx[3];
    float st = rt[0] + rt[1] + rt[2] + rt[3];
    // cross = (LAMBDA/2) * 2*sx / (m(m-1)) = sx/8064
    float score = sx / 8064.f - st / 64.f;
    score = fminf(fmaxf(score, -10.f), 10.f);
    out[0] = score;
  }
}

extern "C" void kernel_launch(void* const* d_in, const int* in_sizes, int n_in,
                              void* d_out, int out_size, void* d_ws, size_t ws_size,
                              hipStream_t stream) {
  const float* X = (const float*)d_in[0];   // generated_samples [64,4096,128]
  const float* T = (const float*)d_in[1];   // target_sample [4096,128]
  // d_in[2] (time_points) is mathematically unused by the reference.
  float* out = (float*)d_out;
  float* G   = (float*)d_ws;

  const int Nk = in_sizes[1];               // S*D = 524288
  const int total_steps = Nk / 32;          // 16384 K-steps

  int NC = (int)(ws_size / (GE * sizeof(float)));
  if (NC > 16) NC = 16;
  if (NC < 1) NC = 1;

  zero_ws<<<64, 256, 0, stream>>>(G, NC * GE);
  gram_k<<<GRID, TPB, 0, stream>>>(X, T, G, NC, Nk, total_steps);
  epilogue_k<<<1, EPT, 0, stream>>>(G, NC, out);
}

// Round 3
// 322.662 us; speedup vs baseline: 1.1353x; 1.1353x over previous
//
#include <hip/hip_runtime.h>
#include <hip/hip_bf16.h>

// m=64 sample rows + 1 target row = 65 rows of Nk = 524288 f32 each.
// Score reduces to the 65x65 Gram matrix + O(m^2) scalar epilogue.
// time_points (d_in[2]) cancels in all pairwise differences -> unused.
//
// R3: canonical staged GEMM-style loop per guide §5:
//  - global_load_lds width=16, coalesced (1KB contiguous per wave-instr),
//    double-buffered, counted vmcnt(9/8) per wave (T4; never drain-0 in loop)
//  - LDS XOR-swizzle via pre-swizzled GLOBAL source (rule 21) so the
//    512B-row-stride ds_read_b128 is 2-way (free) instead of 16-way
//  - atomic-free reduction: 4-round serialized wave add in LDS, plain
//    per-block slice store, separate reduce + epilogue kernels.
#define NROW 65
#define GP   80            // padded gram dim (5 tiles of 16)
#define GE   (GP * GP)     // 6400 f32
#define BK   128           // f32 per row per chunk
#define ROWB (BK * 4)      // 512 B per LDS row
#define RPAD 80            // padded rows per LDS buffer (rows 65..79 garbage)
#define BUFB (RPAD * ROWB) // 40960 B per buffer; x2 = 80 KB -> 2 blocks/CU
#define TPB  256           // 4 waves
#define GRID_MAX 512

typedef float  f32x4  __attribute__((ext_vector_type(4)));
typedef __bf16 bf16x8 __attribute__((ext_vector_type(8)));

__device__ __forceinline__ void gl_lds16(const void* g, void* l) {
  __builtin_amdgcn_global_load_lds(
      (const __attribute__((address_space(1))) void*)g,
      (__attribute__((address_space(3))) void*)l, 16, 0, 0);
}

__global__ __launch_bounds__(TPB) void gram_k(
    const float* __restrict__ X,   // [64][Nk]
    const float* __restrict__ T,   // [Nk]
    float* __restrict__ S,         // [gridDim.x][GE] slice output
    int Nk, int nch)
{
  __shared__ __align__(16) char smem[2 * BUFB];
  const int tid  = threadIdx.x;
  const int wv   = tid >> 6;
  const int lane = tid & 63;
  const int l32  = lane & 31, half = lane >> 5;
  const int lr   = lane & 15, kg = lane >> 4;

  f32x4 acc[15];
#pragma unroll
  for (int i = 0; i < 15; ++i) acc[i] = (f32x4){0.f, 0.f, 0.f, 0.f};

  // Stage chunk c into buf: per wave 8 pair-row loads (rows 2p,2p+1 via lane
  // halves) + wave0 loads row 64 (lanes 0..31). Global source is pre-swizzled
  // so LDS 16B-slot q holds global slot q^((row&7)<<4) within the row.
  auto stage = [&](char* buf, int c) {
#pragma unroll
    for (int i = 0; i < 8; ++i) {
      const int p   = wv + 4 * i;          // 0..31
      const int r0  = 2 * p;
      const int row = r0 + half;
      const char* src = (const char*)(X + (size_t)row * Nk + (size_t)c * BK)
                        + (((l32 * 16) ^ ((row & 7) << 4)));
      gl_lds16(src, buf + r0 * ROWB);
    }
    if (wv == 0 && lane < 32) {            // row 64 = target; (64&7)=0 -> no swz
      const char* src = (const char*)(T + (size_t)c * BK) + l32 * 16;
      gl_lds16(src, buf + 64 * ROWB);
    }
  };

  int c = blockIdx.x;
  stage(smem, c);
  int it = 0;
  while (true) {
    char* cur = smem + (it & 1) * BUFB;
    char* nxt = smem + ((it & 1) ^ 1) * BUFB;
    const int cn = c + gridDim.x;
    const bool has_next = cn < nch;
    if (has_next) stage(nxt, cn);

    // Counted vmcnt: own NEXT loads stay in flight; own CUR loads complete.
    // After s_barrier, all waves' CUR loads are complete (each drained its own).
    if (has_next) {
      if (wv == 0) asm volatile("s_waitcnt vmcnt(9)" ::: "memory");
      else         asm volatile("s_waitcnt vmcnt(8)" ::: "memory");
    } else {
      asm volatile("s_waitcnt vmcnt(0)" ::: "memory");
    }
    __builtin_amdgcn_sched_barrier(0);
    __builtin_amdgcn_s_barrier();
    __builtin_amdgcn_sched_barrier(0);

    // Compute: wave wv owns K-substep wv (32 floats). Fragment = 8 f32 of
    // row (t*16+lr), k-group kg. Rows 65..79 read in-bounds garbage ->
    // only feeds discarded (i>64 or j>64) outputs (MFMA outs independent).
    {
      const int inner = wv * 128 + kg * 32;
      bf16x8 f[5];
#pragma unroll
      for (int t = 0; t < 5; ++t) {
        const int row = t * 16 + lr;
        const char* base = cur + row * ROWB;
        const int swz = (row & 7) << 4;
        f32x4 a = *(const f32x4*)(base + (inner ^ swz));
        f32x4 b = *(const f32x4*)(base + ((inner + 16) ^ swz));
        f[t] = (bf16x8){(__bf16)a.x, (__bf16)a.y, (__bf16)a.z, (__bf16)a.w,
                        (__bf16)b.x, (__bf16)b.y, (__bf16)b.z, (__bf16)b.w};
      }
#pragma unroll
      for (int I = 0; I < 5; ++I)
#pragma unroll
        for (int J = I; J < 5; ++J) {
          const int idx = I * 5 + J - (I * (I + 1)) / 2;
          acc[idx] = __builtin_amdgcn_mfma_f32_16x16x32_bf16(f[I], f[J], acc[idx], 0, 0, 0);
        }
    }
    __builtin_amdgcn_s_barrier();   // cur fully consumed -> next iter may overwrite
    if (!has_next) break;
    c = cn; ++it;
  }

  // Atomic-free block reduction: 4 serialized wave rounds into LDS [80][80]
  // (within a wave each (I,J,r) hits 64 distinct addresses), then coalesced
  // plain store of this block's slice.
  float* gl = (float*)smem;
  __syncthreads();
  for (int e = tid; e < GE; e += TPB) gl[e] = 0.f;
  __syncthreads();
  for (int w = 0; w < 4; ++w) {
    if (wv == w) {
#pragma unroll
      for (int I = 0; I < 5; ++I)
#pragma unroll
        for (int J = I; J < 5; ++J) {
          const int idx = I * 5 + J - (I * (I + 1)) / 2;
#pragma unroll
          for (int r = 0; r < 4; ++r) {
            const int grow = I * 16 + kg * 4 + r;   // C/D: row=(lane>>4)*4+reg
            const int gcol = J * 16 + lr;           //      col=lane&15
            gl[grow * GP + gcol] += acc[idx][r];
          }
        }
    }
    __syncthreads();
  }
  float* dst = S + (size_t)blockIdx.x * GE;
  for (int e = tid; e < GE; e += TPB) dst[e] = gl[e];
}

__global__ __launch_bounds__(128) void reduce_k(
    const float* __restrict__ S, float* __restrict__ G, int nsl)
{
  const int e = blockIdx.x * 128 + threadIdx.x;
  if (e >= GE) return;
  float s = 0.f;
  for (int i = 0; i < nsl; ++i) s += S[(size_t)i * GE + e];
  G[e] = s;
}

__global__ __launch_bounds__(256) void epilogue_k(
    const float* __restrict__ G, float* __restrict__ out)
{
  __shared__ float gl[GE];
  __shared__ float rx[4], rt[4];
  const int tid = threadIdx.x;
  for (int e = tid; e < GE; e += 256) gl[e] = G[e];
  __syncthreads();

  float accX = 0.f, accT = 0.f;
  for (int e = tid; e < GE; e += 256) {
    int i = e / GP, j = e % GP;
    if (j >= NROW || i >= j) continue;           // upper triangle, i<j
    float g  = gl[e];
    float d2 = gl[i * GP + i] + gl[j * GP + j] - 2.f * g;
    if (j < 64) accX += expf(-fmaxf(d2, 0.f));   // pair term (ref clamps d2)
    else        accT += expf(-d2);               // target term (no clamp)
  }
#pragma unroll
  for (int off = 32; off > 0; off >>= 1) {
    accX += __shfl_down(accX, off);
    accT += __shfl_down(accT, off);
  }
  const int wv = tid >> 6, lane = tid & 63;
  if (lane == 0) { rx[wv] = accX; rt[wv] = accT; }
  __syncthreads();
  if (tid == 0) {
    float sx = rx[0] + rx[1] + rx[2] + rx[3];
    float st = rt[0] + rt[1] + rt[2] + rt[3];
    // cross = (LAMBDA/2) * 2*sx / (m(m-1)) = sx/8064
    float score = sx / 8064.f - st / 64.f;
    score = fminf(fmaxf(score, -10.f), 10.f);
    out[0] = score;
  }
}

extern "C" void kernel_launch(void* const* d_in, const int* in_sizes, int n_in,
                              void* d_out, int out_size, void* d_ws, size_t ws_size,
                              hipStream_t stream) {
  const float* X = (const float*)d_in[0];   // generated_samples [64,4096,128]
  const float* T = (const float*)d_in[1];   // target_sample [4096,128]
  float* out = (float*)d_out;

  const int Nk  = in_sizes[1];              // 524288
  const int nch = Nk / BK;                  // 4096

  // ws layout: [nsl][GE] slices | [GE] final G
  int nsl = (int)(ws_size / (GE * sizeof(float))) - 1;
  if (nsl > GRID_MAX) nsl = GRID_MAX;
  if (nsl < 1) nsl = 1;
  float* S = (float*)d_ws;
  float* G = S + (size_t)nsl * GE;

  gram_k<<<nsl, TPB, 0, stream>>>(X, T, S, Nk, nch);
  reduce_k<<<(GE + 127) / 128, 128, 0, stream>>>(S, G, nsl);
  epilogue_k<<<1, 256, 0, stream>>>(G, out);
}

// Round 4
// 211.094 us; speedup vs baseline: 1.7353x; 1.5285x over previous
//
#include <hip/hip_runtime.h>
#include <hip/hip_bf16.h>

// m=64 sample rows + 1 target row = 65 rows of Nk = 524288 f32 each.
// Score reduces to the 65x65 Gram matrix + O(m^2) scalar epilogue.
// time_points (d_in[2]) cancels in all pairwise differences -> unused.
//
// R4: gram_k unchanged from R3 (double-buffered global_load_lds staging,
// counted vmcnt, swizzled LDS, atomic-free slice store). reduce_k rewritten:
// R3's version was 121.7 us -- 6400 threads serially walking 512 slices
// (latency-bound, 1% occupancy). Now 4 threads/element with unrolled
// independent loads + LDS combine.
#define NROW 65
#define GP   80            // padded gram dim (5 tiles of 16)
#define GE   (GP * GP)     // 6400 f32
#define BK   128           // f32 per row per chunk
#define ROWB (BK * 4)      // 512 B per LDS row
#define RPAD 80            // padded rows per LDS buffer (rows 65..79 garbage)
#define BUFB (RPAD * ROWB) // 40960 B per buffer; x2 = 80 KB -> 2 blocks/CU
#define TPB  256           // 4 waves
#define GRID_MAX 512

typedef float  f32x4  __attribute__((ext_vector_type(4)));
typedef __bf16 bf16x8 __attribute__((ext_vector_type(8)));

__device__ __forceinline__ void gl_lds16(const void* g, void* l) {
  __builtin_amdgcn_global_load_lds(
      (const __attribute__((address_space(1))) void*)g,
      (__attribute__((address_space(3))) void*)l, 16, 0, 0);
}

__global__ __launch_bounds__(TPB) void gram_k(
    const float* __restrict__ X,   // [64][Nk]
    const float* __restrict__ T,   // [Nk]
    float* __restrict__ S,         // [gridDim.x][GE] slice output
    int Nk, int nch)
{
  __shared__ __align__(16) char smem[2 * BUFB];
  const int tid  = threadIdx.x;
  const int wv   = tid >> 6;
  const int lane = tid & 63;
  const int l32  = lane & 31, half = lane >> 5;
  const int lr   = lane & 15, kg = lane >> 4;

  f32x4 acc[15];
#pragma unroll
  for (int i = 0; i < 15; ++i) acc[i] = (f32x4){0.f, 0.f, 0.f, 0.f};

  // Stage chunk c into buf: per wave 8 pair-row loads (rows 2p,2p+1 via lane
  // halves) + wave0 loads row 64 (lanes 0..31). Global source is pre-swizzled
  // so LDS 16B-slot q holds global slot q^((row&7)<<4) within the row.
  auto stage = [&](char* buf, int c) {
#pragma unroll
    for (int i = 0; i < 8; ++i) {
      const int p   = wv + 4 * i;          // 0..31
      const int r0  = 2 * p;
      const int row = r0 + half;
      const char* src = (const char*)(X + (size_t)row * Nk + (size_t)c * BK)
                        + (((l32 * 16) ^ ((row & 7) << 4)));
      gl_lds16(src, buf + r0 * ROWB);
    }
    if (wv == 0 && lane < 32) {            // row 64 = target; (64&7)=0 -> no swz
      const char* src = (const char*)(T + (size_t)c * BK) + l32 * 16;
      gl_lds16(src, buf + 64 * ROWB);
    }
  };

  int c = blockIdx.x;
  stage(smem, c);
  int it = 0;
  while (true) {
    char* cur = smem + (it & 1) * BUFB;
    char* nxt = smem + ((it & 1) ^ 1) * BUFB;
    const int cn = c + gridDim.x;
    const bool has_next = cn < nch;
    if (has_next) stage(nxt, cn);

    // Counted vmcnt: own NEXT loads stay in flight; own CUR loads complete.
    // After s_barrier, all waves' CUR loads are complete (each drained its own).
    if (has_next) {
      if (wv == 0) asm volatile("s_waitcnt vmcnt(9)" ::: "memory");
      else         asm volatile("s_waitcnt vmcnt(8)" ::: "memory");
    } else {
      asm volatile("s_waitcnt vmcnt(0)" ::: "memory");
    }
    __builtin_amdgcn_sched_barrier(0);
    __builtin_amdgcn_s_barrier();
    __builtin_amdgcn_sched_barrier(0);

    // Compute: wave wv owns K-substep wv (32 floats). Fragment = 8 f32 of
    // row (t*16+lr), k-group kg. Rows 65..79 read in-bounds garbage ->
    // only feeds discarded (i>64 or j>64) outputs (MFMA outs independent).
    {
      const int inner = wv * 128 + kg * 32;
      bf16x8 f[5];
#pragma unroll
      for (int t = 0; t < 5; ++t) {
        const int row = t * 16 + lr;
        const char* base = cur + row * ROWB;
        const int swz = (row & 7) << 4;
        f32x4 a = *(const f32x4*)(base + (inner ^ swz));
        f32x4 b = *(const f32x4*)(base + ((inner + 16) ^ swz));
        f[t] = (bf16x8){(__bf16)a.x, (__bf16)a.y, (__bf16)a.z, (__bf16)a.w,
                        (__bf16)b.x, (__bf16)b.y, (__bf16)b.z, (__bf16)b.w};
      }
#pragma unroll
      for (int I = 0; I < 5; ++I)
#pragma unroll
        for (int J = I; J < 5; ++J) {
          const int idx = I * 5 + J - (I * (I + 1)) / 2;
          acc[idx] = __builtin_amdgcn_mfma_f32_16x16x32_bf16(f[I], f[J], acc[idx], 0, 0, 0);
        }
    }
    __builtin_amdgcn_s_barrier();   // cur fully consumed -> next iter may overwrite
    if (!has_next) break;
    c = cn; ++it;
  }

  // Atomic-free block reduction: 4 serialized wave rounds into LDS [80][80]
  // (within a wave each (I,J,r) hits 64 distinct addresses), then coalesced
  // plain store of this block's slice.
  float* gl = (float*)smem;
  __syncthreads();
  for (int e = tid; e < GE; e += TPB) gl[e] = 0.f;
  __syncthreads();
  for (int w = 0; w < 4; ++w) {
    if (wv == w) {
#pragma unroll
      for (int I = 0; I < 5; ++I)
#pragma unroll
        for (int J = I; J < 5; ++J) {
          const int idx = I * 5 + J - (I * (I + 1)) / 2;
#pragma unroll
          for (int r = 0; r < 4; ++r) {
            const int grow = I * 16 + kg * 4 + r;   // C/D: row=(lane>>4)*4+reg
            const int gcol = J * 16 + lr;           //      col=lane&15
            gl[grow * GP + gcol] += acc[idx][r];
          }
        }
    }
    __syncthreads();
  }
  float* dst = S + (size_t)blockIdx.x * GE;
  for (int e = tid; e < GE; e += TPB) dst[e] = gl[e];
}

// R4: parallel slice reduction. 100 blocks x 256 threads; block owns 64
// consecutive elements; 4 threads per element stride the slices (independent
// loads, unrolled 8 deep); LDS combine. Per-iteration a wave reads 256 B
// contiguous. Replaces R3's 121.7 us serial version.
#define RBLK 64
__global__ __launch_bounds__(256) void reduce_k(
    const float* __restrict__ S, float* __restrict__ G, int nsl)
{
  __shared__ float ps[4][RBLK];
  const int tid = threadIdx.x;
  const int e0  = blockIdx.x * RBLK;
  const int el  = tid & (RBLK - 1);
  const int p   = tid >> 6;            // 0..3
  const float* base = S + (size_t)p * GE + (e0 + el);
  float s = 0.f;
  int i = p;
#pragma unroll 8
  for (; i + 32 <= nsl; i += 32) {     // 8 unrolled x stride-4 slices
    s += base[0];
    s += base[(size_t)4  * GE];
    s += base[(size_t)8  * GE];
    s += base[(size_t)12 * GE];
    s += base[(size_t)16 * GE];
    s += base[(size_t)20 * GE];
    s += base[(size_t)24 * GE];
    s += base[(size_t)28 * GE];
    base += (size_t)32 * GE;
  }
  for (; i < nsl; i += 4) { s += base[0]; base += (size_t)4 * GE; }
  ps[p][el] = s;
  __syncthreads();
  if (tid < RBLK)
    G[e0 + tid] = ps[0][tid] + ps[1][tid] + ps[2][tid] + ps[3][tid];
}

__global__ __launch_bounds__(256) void epilogue_k(
    const float* __restrict__ G, float* __restrict__ out)
{
  __shared__ float gl[GE];
  __shared__ float rx[4], rt[4];
  const int tid = threadIdx.x;
  for (int e = tid; e < GE; e += 256) gl[e] = G[e];
  __syncthreads();

  float accX = 0.f, accT = 0.f;
  for (int e = tid; e < GE; e += 256) {
    int i = e / GP, j = e % GP;
    if (j >= NROW || i >= j) continue;           // upper triangle, i<j
    float g  = gl[e];
    float d2 = gl[i * GP + i] + gl[j * GP + j] - 2.f * g;
    if (j < 64) accX += expf(-fmaxf(d2, 0.f));   // pair term (ref clamps d2)
    else        accT += expf(-d2);               // target term (no clamp)
  }
#pragma unroll
  for (int off = 32; off > 0; off >>= 1) {
    accX += __shfl_down(accX, off);
    accT += __shfl_down(accT, off);
  }
  const int wv = tid >> 6, lane = tid & 63;
  if (lane == 0) { rx[wv] = accX; rt[wv] = accT; }
  __syncthreads();
  if (tid == 0) {
    float sx = rx[0] + rx[1] + rx[2] + rx[3];
    float st = rt[0] + rt[1] + rt[2] + rt[3];
    // cross = (LAMBDA/2) * 2*sx / (m(m-1)) = sx/8064
    float score = sx / 8064.f - st / 64.f;
    score = fminf(fmaxf(score, -10.f), 10.f);
    out[0] = score;
  }
}

extern "C" void kernel_launch(void* const* d_in, const int* in_sizes, int n_in,
                              void* d_out, int out_size, void* d_ws, size_t ws_size,
                              hipStream_t stream) {
  const float* X = (const float*)d_in[0];   // generated_samples [64,4096,128]
  const float* T = (const float*)d_in[1];   // target_sample [4096,128]
  float* out = (float*)d_out;

  const int Nk  = in_sizes[1];              // 524288
  const int nch = Nk / BK;                  // 4096

  // ws layout: [nsl][GE] slices | [GE] final G
  int nsl = (int)(ws_size / (GE * sizeof(float))) - 1;
  if (nsl > GRID_MAX) nsl = GRID_MAX;
  if (nsl < 1) nsl = 1;
  float* S = (float*)d_ws;
  float* G = S + (size_t)nsl * GE;

  gram_k<<<nsl, TPB, 0, stream>>>(X, T, S, Nk, nch);
  reduce_k<<<(GE / RBLK), 256, 0, stream>>>(S, G, nsl);
  epilogue_k<<<1, 256, 0, stream>>>(G, out);
}

// Round 5
// 209.973 us; speedup vs baseline: 1.7446x; 1.0053x over previous
//
#include <hip/hip_runtime.h>
#include <hip/hip_bf16.h>

// m=64 sample rows + 1 target row = 65 rows of Nk = 524288 f32 each.
// Score reduces to the 65x65 Gram matrix + O(m^2) scalar epilogue.
// time_points (d_in[2]) cancels in all pairwise differences -> unused.
//
// R5: gram_k restructured as WAVE-PRIVATE streams. R1-R4 staged per-BLOCK
// with 2 barriers per chunk -> whole block advances at the slowest wave's
// load latency; measured ~1.8 TB/s effective vs 6.9 TB/s the same machine
// sustains on the harness fills. Now: each wave owns a private double-
// buffered LDS region (2 x 8448 B), stages its own 65-row x 128 B chunk
// with 9 contiguous 1 KB global_load_lds, counted vmcnt(9), NO barriers in
// the hot loop. 512 blocks x 4 waves = 2048 independent streams, 8 chunks
// each. LDS 66 KB/block -> 2 blocks/CU.
#define NROW 65
#define GP   80            // padded gram dim (5 tiles of 16)
#define GE   (GP * GP)     // 6400 f32
#define CHF  32            // f32 per row per chunk (one MFMA K-step)
#define ROWB 128           // bytes per LDS row (CHF*4)
#define NRB  66            // rows per buffer: 65 real + 1 garbage (reads clamp)
#define BUFB (NRB * ROWB)  // 8448 B
#define WBUF (2 * BUFB)    // per-wave double buffer
#define TPB  256           // 4 waves
#define GRID_MAX 512

typedef float  f32x4  __attribute__((ext_vector_type(4)));
typedef __bf16 bf16x8 __attribute__((ext_vector_type(8)));

__device__ __forceinline__ void gl_lds16(const void* g, void* l) {
  __builtin_amdgcn_global_load_lds(
      (const __attribute__((address_space(1))) void*)g,
      (__attribute__((address_space(3))) void*)l, 16, 0, 0);
}

__global__ __launch_bounds__(TPB) void gram_k(
    const float* __restrict__ X,   // [64][Nk]
    const float* __restrict__ T,   // [Nk]
    float* __restrict__ S,         // [gridDim.x][GE] slice output
    int Nk, int nch)
{
  // 4 waves x 16896 B = 67584 B; tail reduction reuses the first 25600 B.
  __shared__ __align__(16) char smem[4 * WBUF];
  const int tid  = threadIdx.x;
  const int wv   = tid >> 6;
  const int lane = tid & 63;
  const int lr   = lane & 15, kg = lane >> 4;
  const size_t Nkb = (size_t)Nk * 4;

  char* myb = smem + wv * WBUF;

  f32x4 acc[15];
#pragma unroll
  for (int i = 0; i < 15; ++i) acc[i] = (f32x4){0.f, 0.f, 0.f, 0.f};

  // Stage chunk c into this wave's buffer: 8 instrs x 8 rows x 128 B + 1
  // partial instr for row 64 (target). LDS dest is linear (gload_lds writes
  // base + lane*16); source is pre-swizzled so physical 16B-slot p of row r
  // holds global slot p^(r&7)  (rule 21: linear dest + inv-swz src + swz read).
  auto stage = [&](char* buf, int c) {
    const size_t colb = (size_t)c * ROWB;
#pragma unroll
    for (int i = 0; i < 8; ++i) {
      const int r  = 8 * i + (lane >> 3);
      const int ss = (lane & 7) ^ ((lane >> 3) & 7);   // (l&7)^(r&7)
      const char* src = (const char*)X + (size_t)r * Nkb + colb + ss * 16;
      gl_lds16(src, buf + i * 1024);
    }
    if (lane < 8) {                    // row 64; (64&7)=0 -> no swizzle
      const char* src = (const char*)T + colb + lane * 16;
      gl_lds16(src, buf + 64 * ROWB);
    }
  };

  const int nwaves = gridDim.x * (TPB / 64);
  int c = blockIdx.x * (TPB / 64) + wv;
  stage(myb, c);
  int it = 0;
  while (true) {
    char* cur = myb + (it & 1) * BUFB;
    char* nxt = myb + ((it & 1) ^ 1) * BUFB;
    const int cn = c + nwaves;
    const bool hn = cn < nch;
    // Previous iteration's ds_reads are consumed; pin order, then issue
    // next-chunk loads so they fly during this chunk's compute.
    asm volatile("s_waitcnt lgkmcnt(0)" ::: "memory");
    __builtin_amdgcn_sched_barrier(0);
    if (hn) stage(nxt, cn);
    if (hn) asm volatile("s_waitcnt vmcnt(9)" ::: "memory");  // cur complete
    else    asm volatile("s_waitcnt vmcnt(0)" ::: "memory");
    __builtin_amdgcn_sched_barrier(0);

    // Fragments: tile t, lane holds 8 f32 of row t*16+lr at float-offset
    // kg*8 within the 32-f32 chunk. Rows >65 clamp to garbage row 65 ->
    // only pollutes G entries with i or j >= 65, which epilogue discards.
    bf16x8 f[5];
#pragma unroll
    for (int t = 0; t < 5; ++t) {
      int r = t * 16 + lr; if (r > 65) r = 65;
      const char* rb = cur + r * ROWB;
      const int sw = (r & 7) << 4;
      f32x4 a = *(const f32x4*)(rb + ((kg * 32) ^ sw));
      f32x4 b = *(const f32x4*)(rb + ((kg * 32 + 16) ^ sw));
      f[t] = (bf16x8){(__bf16)a.x, (__bf16)a.y, (__bf16)a.z, (__bf16)a.w,
                      (__bf16)b.x, (__bf16)b.y, (__bf16)b.z, (__bf16)b.w};
    }
#pragma unroll
    for (int I = 0; I < 5; ++I)
#pragma unroll
      for (int J = I; J < 5; ++J) {
        const int idx = I * 5 + J - (I * (I + 1)) / 2;
        acc[idx] = __builtin_amdgcn_mfma_f32_16x16x32_bf16(f[I], f[J], acc[idx], 0, 0, 0);
      }
    if (!hn) break;
    c = cn; ++it;
  }

  // Atomic-free block reduction: serialized wave rounds into LDS [80][80]
  // (reuses staging memory), then coalesced store of this block's slice.
  float* gl = (float*)smem;
  __syncthreads();
  for (int e = tid; e < GE; e += TPB) gl[e] = 0.f;
  __syncthreads();
  for (int w = 0; w < 4; ++w) {
    if (wv == w) {
#pragma unroll
      for (int I = 0; I < 5; ++I)
#pragma unroll
        for (int J = I; J < 5; ++J) {
          const int idx = I * 5 + J - (I * (I + 1)) / 2;
#pragma unroll
          for (int r = 0; r < 4; ++r) {
            const int grow = I * 16 + kg * 4 + r;   // C/D: row=(lane>>4)*4+reg
            const int gcol = J * 16 + lr;           //      col=lane&15
            gl[grow * GP + gcol] += acc[idx][r];
          }
        }
    }
    __syncthreads();
  }
  float* dst = S + (size_t)blockIdx.x * GE;
  for (int e = tid; e < GE; e += TPB) dst[e] = gl[e];
}

// R4 parallel slice reduction (measured fix: 121.7 us -> ~8 us).
#define RBLK 64
__global__ __launch_bounds__(256) void reduce_k(
    const float* __restrict__ S, float* __restrict__ G, int nsl)
{
  __shared__ float ps[4][RBLK];
  const int tid = threadIdx.x;
  const int e0  = blockIdx.x * RBLK;
  const int el  = tid & (RBLK - 1);
  const int p   = tid >> 6;            // 0..3
  const float* base = S + (size_t)p * GE + (e0 + el);
  float s = 0.f;
  int i = p;
#pragma unroll 8
  for (; i + 32 <= nsl; i += 32) {
    s += base[0];
    s += base[(size_t)4  * GE];
    s += base[(size_t)8  * GE];
    s += base[(size_t)12 * GE];
    s += base[(size_t)16 * GE];
    s += base[(size_t)20 * GE];
    s += base[(size_t)24 * GE];
    s += base[(size_t)28 * GE];
    base += (size_t)32 * GE;
  }
  for (; i < nsl; i += 4) { s += base[0]; base += (size_t)4 * GE; }
  ps[p][el] = s;
  __syncthreads();
  if (tid < RBLK)
    G[e0 + tid] = ps[0][tid] + ps[1][tid] + ps[2][tid] + ps[3][tid];
}

__global__ __launch_bounds__(256) void epilogue_k(
    const float* __restrict__ G, float* __restrict__ out)
{
  __shared__ float gl[GE];
  __shared__ float rx[4], rt[4];
  const int tid = threadIdx.x;
  for (int e = tid; e < GE; e += 256) gl[e] = G[e];
  __syncthreads();

  float accX = 0.f, accT = 0.f;
  for (int e = tid; e < GE; e += 256) {
    int i = e / GP, j = e % GP;
    if (j >= NROW || i >= j) continue;           // upper triangle, i<j
    float g  = gl[e];
    float d2 = gl[i * GP + i] + gl[j * GP + j] - 2.f * g;
    if (j < 64) accX += expf(-fmaxf(d2, 0.f));   // pair term (ref clamps d2)
    else        accT += expf(-d2);               // target term (no clamp)
  }
#pragma unroll
  for (int off = 32; off > 0; off >>= 1) {
    accX += __shfl_down(accX, off);
    accT += __shfl_down(accT, off);
  }
  const int wv = tid >> 6, lane = tid & 63;
  if (lane == 0) { rx[wv] = accX; rt[wv] = accT; }
  __syncthreads();
  if (tid == 0) {
    float sx = rx[0] + rx[1] + rx[2] + rx[3];
    float st = rt[0] + rt[1] + rt[2] + rt[3];
    // cross = (LAMBDA/2) * 2*sx / (m(m-1)) = sx/8064
    float score = sx / 8064.f - st / 64.f;
    score = fminf(fmaxf(score, -10.f), 10.f);
    out[0] = score;
  }
}

extern "C" void kernel_launch(void* const* d_in, const int* in_sizes, int n_in,
                              void* d_out, int out_size, void* d_ws, size_t ws_size,
                              hipStream_t stream) {
  const float* X = (const float*)d_in[0];   // generated_samples [64,4096,128]
  const float* T = (const float*)d_in[1];   // target_sample [4096,128]
  float* out = (float*)d_out;

  const int Nk  = in_sizes[1];              // 524288
  const int nch = Nk / CHF;                 // 16384 chunks of 32 f32

  // ws layout: [nsl][GE] slices | [GE] final G
  int nsl = (int)(ws_size / (GE * sizeof(float))) - 1;
  if (nsl > GRID_MAX) nsl = GRID_MAX;
  if (nsl < 1) nsl = 1;
  float* S = (float*)d_ws;
  float* G = S + (size_t)nsl * GE;

  gram_k<<<nsl, TPB, 0, stream>>>(X, T, S, Nk, nch);
  reduce_k<<<(GE / RBLK), 256, 0, stream>>>(S, G, nsl);
  epilogue_k<<<1, 256, 0, stream>>>(G, out);
}